// Round 1
// 516.927 us; speedup vs baseline: 1.8519x; 1.8519x over previous
//
#include <hip/hip_runtime.h>

typedef _Float16 f16;
typedef _Float16 f16x8 __attribute__((ext_vector_type(8)));
typedef float f32x4 __attribute__((ext_vector_type(4)));

#define N_TOT   8192
#define L_STEPS 32
#define H_DIM   256
#define G4      1024
#define OUT_DIM 128
#define BN      32
#define NBLK    256
#define THREADS 512

// workspace layout (bytes):
//   Wpack : 262144 f16 = 524288 B @ 0        (W_hh in B-frag order)
//   fcpack:  32768 f16 =  65536 B @ 524288   (fc_w in B-frag order)
//   bsum  :   1024 f32 =   4096 B @ 589824   (b_ih + b_hh)
#define WPACK_OFF  0
#define FCPACK_OFF 524288
#define BSUM_OFF   589824

__global__ __launch_bounds__(256) void prep_kernel(
    const float* __restrict__ W_hh, const float* __restrict__ fc_w,
    const float* __restrict__ b_ih, const float* __restrict__ b_hh,
    f16* __restrict__ Wpack, f16* __restrict__ fcpack, float* __restrict__ bsum)
{
    int p = blockIdx.x * blockDim.x + threadIdx.x;
    if (p < 262144) {
        // Wpack[((kb*64 + T)*64 + lane)*8 + e] = W_hh[g][k]
        // g = 16*T + (lane&15), k = 32*kb + 8*(lane>>4) + e
        int e = p & 7, lane = (p >> 3) & 63, T = (p >> 9) & 63, kb = p >> 15;
        int g = 16 * T + (lane & 15);
        int k = 32 * kb + 8 * (lane >> 4) + e;
        Wpack[p] = (f16)W_hh[g * 256 + k];
    } else if (p < 262144 + 32768) {
        int p2 = p - 262144;
        // fcpack[((kb*8 + ot)*64 + lane)*8 + e] = fc_w[o][k]
        int e = p2 & 7, lane = (p2 >> 3) & 63, ot = (p2 >> 9) & 7, kb = p2 >> 12;
        int o = 16 * ot + (lane & 15);
        int k = 32 * kb + 8 * (lane >> 4) + e;
        fcpack[p2] = (f16)fc_w[o * 256 + k];
    } else if (p < 262144 + 32768 + 1024) {
        int g = p - 262144 - 32768;
        bsum[g] = b_ih[g] + b_hh[g];
    }
}

__device__ __forceinline__ float sigmoid_(float x) {
    return 1.0f / (1.0f + __expf(-x));
}
__device__ __forceinline__ float tanh_(float x) {
    float t = __expf(-2.0f * x);
    return (1.0f - t) / (1.0f + t);
}

// 256 blocks x 512 threads (8 waves, 2 waves/SIMD, 1 block/CU).
// W_hh B-frags are STREAMED from L2 (512 KB Wpack is resident per XCD: all
// 32 blocks on an XCD read the same bytes) through a 2-deep register pipe:
// per kb-phase, issue loads for kb+1 (8 frags = 32 VGPRs) then MFMA kb.
// kb=7 prefetches kb=0 of the NEXT step (weights are step-invariant); the
// prefetch drains at the __syncthreads after the ~500-cycle elementwise
// phase, so its latency is hidden. fc B-frags (32 VGPR/wave) stay resident.
// NOTE: full register residency of W_hh (the previous design) needs 256
// VGPR/wave for weights alone -> compiler spilled to scratch -> 1.8 GB HBM
// fetch. The asm pointer barrier below stops LICM from re-hoisting the
// (loop-invariant, __restrict__) weight loads and recreating that spill.
__global__ __launch_bounds__(THREADS, 2) void lstm_kernel(
    const float* __restrict__ x, const float* __restrict__ W_ih,
    const f16* __restrict__ Wpack, const float* __restrict__ bsum,
    const f16* __restrict__ fcpack, const float* __restrict__ fc_b,
    float* __restrict__ out)
{
    __shared__ __align__(16) f16 hp[2][8192];          // h in A-frag order, dbuf
    __shared__ __align__(16) float obuf[BN * OUT_DIM]; // fc out staging, 16 KB

    const int tid  = threadIdx.x;
    const int wave = tid >> 6;
    const int lane = tid & 63;
    const int l15  = lane & 15;
    const int lq   = lane >> 4;
    const int n0   = blockIdx.x * BN;

    // ---- resident fc B-frags (8 KB/wave -> 32 VGPR) ----
    f16x8 fcw[8];
#pragma unroll
    for (int kb = 0; kb < 8; ++kb)
        fcw[kb] = *(const f16x8*)&fcpack[((kb * 8 + wave) * 64 + lane) * 8];

    // h(t=0) = 0
    for (int i = tid; i < 8192; i += THREADS) hp[0][i] = (f16)0.0f;

    // per-lane x-projection constants: g = 256*q + 16*(wave + 8*ti) + l15
    float wih0[2][4], wih1[2][4], bsv[2][4];
#pragma unroll
    for (int ti = 0; ti < 2; ++ti)
#pragma unroll
        for (int q = 0; q < 4; ++q) {
            int g = 256 * q + 16 * (wave + 8 * ti) + l15;
            wih0[ti][q] = W_ih[g * 2 + 0];
            wih1[ti][q] = W_ih[g * 2 + 1];
            bsv[ti][q]  = bsum[g];
        }
    const float fcbv = fc_b[16 * wave + l15];

    float c[2][2][4];
#pragma unroll
    for (int ti = 0; ti < 2; ++ti)
#pragma unroll
        for (int mt = 0; mt < 2; ++mt)
#pragma unroll
            for (int r = 0; r < 4; ++r) c[ti][mt][r] = 0.0f;

    // weight stream base: f16 index = kb*32768 + q*8192 + ti*4096 + wave*512 + lane*8
    unsigned long long wb_u =
        (unsigned long long)(uintptr_t)(Wpack + wave * 512 + lane * 8);

    // prologue: kb=0 tile into buffer 0
    f16x8 wbuf[2][2][4];  // [kb&1][ti][q] — all indices compile-time
    {
        const f16* wb = (const f16*)(uintptr_t)wb_u;
#pragma unroll
        for (int ti = 0; ti < 2; ++ti)
#pragma unroll
            for (int q = 0; q < 4; ++q)
                wbuf[0][ti][q] = *(const f16x8*)&wb[q * 8192 + ti * 4096];
    }

    __syncthreads();

    int buf = 0;
#pragma unroll 1
    for (int l = 0; l < L_STEPS; ++l) {
        // Defeat LICM: make the weight base a fresh value each step so the
        // 64 loop-invariant B-frag loads cannot be hoisted (-> 256-VGPR
        // live set -> scratch spill, the bug this revision removes).
        asm volatile("" : "+v"(wb_u));
        const f16* wb = (const f16*)(uintptr_t)wb_u;

        // ---- accumulator init = x-projection (fp32 exact) ----
        // x is 8 KB/block -> L1-resident after step 0; no prefetch needed.
        f32x4 acc[2][2][4];  // [ti][mt][q]
#pragma unroll
        for (int mt = 0; mt < 2; ++mt)
#pragma unroll
            for (int r = 0; r < 4; ++r) {
                int n = n0 + 16 * mt + 4 * lq + r;
                float2 xv = *(const float2*)&x[(n * L_STEPS + l) * 2];
#pragma unroll
                for (int ti = 0; ti < 2; ++ti)
#pragma unroll
                    for (int q = 0; q < 4; ++q)
                        acc[ti][mt][q][r] = bsv[ti][q] + xv.x * wih0[ti][q]
                                                       + xv.y * wih1[ti][q];
            }

        // ---- gates += h @ W_hh^T (B streamed from L2, A from LDS) ----
#pragma unroll
        for (int kb = 0; kb < 8; ++kb) {
            const int nkb = (kb + 1) & 7;  // kb=7 prefetches next step's kb=0
#pragma unroll
            for (int ti = 0; ti < 2; ++ti)
#pragma unroll
                for (int q = 0; q < 4; ++q)
                    wbuf[nkb & 1][ti][q] =
                        *(const f16x8*)&wb[nkb * 32768 + q * 8192 + ti * 4096];

            f16x8 a0 = *(const f16x8*)&hp[buf][((kb * 2 + 0) * 64 + lane) * 8];
            f16x8 a1 = *(const f16x8*)&hp[buf][((kb * 2 + 1) * 64 + lane) * 8];
#pragma unroll
            for (int ti = 0; ti < 2; ++ti)
#pragma unroll
                for (int q = 0; q < 4; ++q) {
                    acc[ti][0][q] = __builtin_amdgcn_mfma_f32_16x16x32_f16(
                        a0, wbuf[kb & 1][ti][q], acc[ti][0][q], 0, 0, 0);
                    acc[ti][1][q] = __builtin_amdgcn_mfma_f32_16x16x32_f16(
                        a1, wbuf[kb & 1][ti][q], acc[ti][1][q], 0, 0, 0);
                }
        }

        // ---- elementwise LSTM update (all 4 gates in-register per lane) ----
#pragma unroll
        for (int ti = 0; ti < 2; ++ti) {
            int j   = 16 * (wave + 8 * ti) + l15;
            int kbj = j >> 5, qk = (j >> 3) & 3, e = j & 7;
#pragma unroll
            for (int mt = 0; mt < 2; ++mt)
#pragma unroll
                for (int r = 0; r < 4; ++r) {
                    float gi = acc[ti][mt][0][r];
                    float gf = acc[ti][mt][1][r];
                    float gg = acc[ti][mt][2][r];
                    float go = acc[ti][mt][3][r];
                    float cn = sigmoid_(gf) * c[ti][mt][r] + sigmoid_(gi) * tanh_(gg);
                    c[ti][mt][r] = cn;
                    float hv = sigmoid_(go) * tanh_(cn);
                    int laneA = (4 * lq + r) | (qk << 4);
                    hp[buf ^ 1][((kbj * 2 + mt) * 64 + laneA) * 8 + e] = (f16)hv;
                }
        }
        __syncthreads();  // barrier A: h_new visible (also drains kb=0 prefetch)

        // ---- out[:, l, :] = h_new @ fc_w^T + fc_b (B register-resident) ----
        f32x4 facc0 = {fcbv, fcbv, fcbv, fcbv};
        f32x4 facc1 = facc0;
#pragma unroll
        for (int kb = 0; kb < 8; ++kb) {
            f16x8 a0 = *(const f16x8*)&hp[buf ^ 1][((kb * 2 + 0) * 64 + lane) * 8];
            f16x8 a1 = *(const f16x8*)&hp[buf ^ 1][((kb * 2 + 1) * 64 + lane) * 8];
            facc0 = __builtin_amdgcn_mfma_f32_16x16x32_f16(a0, fcw[kb], facc0, 0, 0, 0);
            facc1 = __builtin_amdgcn_mfma_f32_16x16x32_f16(a1, fcw[kb], facc1, 0, 0, 0);
        }
        const int o = 16 * wave + l15;
#pragma unroll
        for (int r = 0; r < 4; ++r) {
            obuf[(4 * lq + r) * OUT_DIM + o]        = facc0[r];
            obuf[(16 + 4 * lq + r) * OUT_DIM + o]   = facc1[r];
        }
        __syncthreads();  // barrier B: obuf visible

        // ---- cooperative, line-contiguous global write ----
        {
            const int row = tid >> 4;
            const int gl  = ((n0 + row) * L_STEPS + l) * OUT_DIM;
#pragma unroll
            for (int half = 0; half < 2; ++half) {
                int col = (tid & 15) * 4 + half * 64;
                f32x4 v = *(const f32x4*)&obuf[row * OUT_DIM + col];
                *(f32x4*)&out[gl + col] = v;
            }
        }

        buf ^= 1;
    }
}

extern "C" void kernel_launch(void* const* d_in, const int* in_sizes, int n_in,
                              void* d_out, int out_size, void* d_ws, size_t ws_size,
                              hipStream_t stream) {
    const float* x    = (const float*)d_in[0];
    const float* W_ih = (const float*)d_in[1];
    const float* W_hh = (const float*)d_in[2];
    const float* b_ih = (const float*)d_in[3];
    const float* b_hh = (const float*)d_in[4];
    const float* fc_w = (const float*)d_in[5];
    const float* fc_b = (const float*)d_in[6];
    float* out = (float*)d_out;

    char* ws = (char*)d_ws;
    f16*   Wpack  = (f16*)(ws + WPACK_OFF);
    f16*   fcpack = (f16*)(ws + FCPACK_OFF);
    float* bsum   = (float*)(ws + BSUM_OFF);

    const int prep_elems = 262144 + 32768 + 1024;
    prep_kernel<<<(prep_elems + 255) / 256, 256, 0, stream>>>(
        W_hh, fc_w, b_ih, b_hh, Wpack, fcpack, bsum);

    lstm_kernel<<<NBLK, THREADS, 0, stream>>>(
        x, W_ih, Wpack, bsum, fcpack, fc_b, out);
}

// Round 2
// 466.128 us; speedup vs baseline: 2.0537x; 1.1090x over previous
//
#include <hip/hip_runtime.h>

typedef _Float16 f16;
typedef _Float16 f16x8 __attribute__((ext_vector_type(8)));
typedef float f32x4 __attribute__((ext_vector_type(4)));

#define N_TOT   8192
#define L_STEPS 32
#define H_DIM   256
#define G4      1024
#define OUT_DIM 128
#define BN      32
#define NBLK    256
#define THREADS 512

// workspace layout (bytes):
//   Wpack : 262144 f16 = 524288 B @ 0        (W_hh in B-frag order)
//   fcpack:  32768 f16 =  65536 B @ 524288   (fc_w in B-frag order)
//   bsum  :   1024 f32 =   4096 B @ 589824   (b_ih + b_hh)
#define WPACK_OFF  0
#define FCPACK_OFF 524288
#define BSUM_OFF   589824

__global__ __launch_bounds__(256) void prep_kernel(
    const float* __restrict__ W_hh, const float* __restrict__ fc_w,
    const float* __restrict__ b_ih, const float* __restrict__ b_hh,
    f16* __restrict__ Wpack, f16* __restrict__ fcpack, float* __restrict__ bsum)
{
    int p = blockIdx.x * blockDim.x + threadIdx.x;
    if (p < 262144) {
        // Wpack[((kb*64 + T)*64 + lane)*8 + e] = W_hh[g][k]
        // g = 16*T + (lane&15), k = 32*kb + 8*(lane>>4) + e
        int e = p & 7, lane = (p >> 3) & 63, T = (p >> 9) & 63, kb = p >> 15;
        int g = 16 * T + (lane & 15);
        int k = 32 * kb + 8 * (lane >> 4) + e;
        Wpack[p] = (f16)W_hh[g * 256 + k];
    } else if (p < 262144 + 32768) {
        int p2 = p - 262144;
        // fcpack[((kb*8 + ot)*64 + lane)*8 + e] = fc_w[o][k]
        int e = p2 & 7, lane = (p2 >> 3) & 63, ot = (p2 >> 9) & 7, kb = p2 >> 12;
        int o = 16 * ot + (lane & 15);
        int k = 32 * kb + 8 * (lane >> 4) + e;
        fcpack[p2] = (f16)fc_w[o * 256 + k];
    } else if (p < 262144 + 32768 + 1024) {
        int g = p - 262144 - 32768;
        bsum[g] = b_ih[g] + b_hh[g];
    }
}

__device__ __forceinline__ float sigmoid_(float x) {
    return 1.0f / (1.0f + __expf(-x));
}
__device__ __forceinline__ float tanh_(float x) {
    float t = __expf(-2.0f * x);
    return (1.0f - t) / (1.0f + t);
}

// Raw barrier with LDS-only ordering: ds ops must complete (lgkmcnt), but
// weight prefetch loads and output global stores stay IN FLIGHT across the
// barrier. __syncthreads() would emit s_waitcnt vmcnt(0) before s_barrier,
// forcing a full HBM store-ack + L2 prefetch drain every step — the main
// serializer of the previous revision.
__device__ __forceinline__ void lds_barrier() {
    asm volatile("s_waitcnt lgkmcnt(0)" ::: "memory");
    __builtin_amdgcn_s_barrier();
    asm volatile("" ::: "memory");
}

// 256 blocks x 512 threads (8 waves, 2 waves/SIMD, 1 block/CU).
// W_hh B-frags are STREAMED from L2 (512 KB Wpack resident per XCD L2)
// through a 2-slot register pipe: per kb-phase, issue loads for the next
// phase, MFMA the current. Phase 7 prefetches the first phase of the NEXT
// step; with lgkm-only barriers those loads stay in flight across the
// elementwise + fc + store phases (~1000 cyc of cover).
// kb sweep is ROTATED per block (kb0 = (blockIdx>>3)&7) so the 32 CUs
// sharing one XCD-L2 hit different 64 KB regions at any instant instead of
// hammering the same banks in lockstep. kb-accumulation order is
// commutative in fp32, so rotation is exact.
__global__ __launch_bounds__(THREADS, 2) void lstm_kernel(
    const float* __restrict__ x, const float* __restrict__ W_ih,
    const f16* __restrict__ Wpack, const float* __restrict__ bsum,
    const f16* __restrict__ fcpack, const float* __restrict__ fc_b,
    float* __restrict__ out)
{
    __shared__ __align__(16) f16 hp[2][8192];          // h in A-frag order, dbuf
    __shared__ __align__(16) float obuf[BN * OUT_DIM]; // fc out staging, 16 KB

    const int tid  = threadIdx.x;
    const int wave = tid >> 6;
    const int lane = tid & 63;
    const int l15  = lane & 15;
    const int lq   = lane >> 4;
    const int n0   = blockIdx.x * BN;
    const int kb0  = (blockIdx.x >> 3) & 7;   // L2 de-hotspot rotation

    // ---- resident fc B-frags (8 KB/wave -> 32 VGPR) ----
    f16x8 fcw[8];
#pragma unroll
    for (int kb = 0; kb < 8; ++kb)
        fcw[kb] = *(const f16x8*)&fcpack[((kb * 8 + wave) * 64 + lane) * 8];

    // h(t=0) = 0
    for (int i = tid; i < 8192; i += THREADS) hp[0][i] = (f16)0.0f;

    // per-lane x-projection constants: g = 256*q + 16*(wave + 8*ti) + l15
    float wih0[2][4], wih1[2][4], bsv[2][4];
#pragma unroll
    for (int ti = 0; ti < 2; ++ti)
#pragma unroll
        for (int q = 0; q < 4; ++q) {
            int g = 256 * q + 16 * (wave + 8 * ti) + l15;
            wih0[ti][q] = W_ih[g * 2 + 0];
            wih1[ti][q] = W_ih[g * 2 + 1];
            bsv[ti][q]  = bsum[g];
        }
    const float fcbv = fc_b[16 * wave + l15];

    float c[2][2][4];
#pragma unroll
    for (int ti = 0; ti < 2; ++ti)
#pragma unroll
        for (int mt = 0; mt < 2; ++mt)
#pragma unroll
            for (int r = 0; r < 4; ++r) c[ti][mt][r] = 0.0f;

    // weight stream base: f16 index = kb*32768 + q*8192 + ti*4096 + wave*512 + lane*8
    unsigned long long wb_u =
        (unsigned long long)(uintptr_t)(Wpack + wave * 512 + lane * 8);

    // prologue: rotated phase-0 tile (kb = kb0) into slot 0
    f16x8 wbuf[2][2][4];  // [slot][ti][q] — slot index always compile-time
    {
        const f16* wb = (const f16*)(uintptr_t)wb_u;
#pragma unroll
        for (int ti = 0; ti < 2; ++ti)
#pragma unroll
            for (int q = 0; q < 4; ++q)
                wbuf[0][ti][q] = *(const f16x8*)&wb[kb0 * 32768 + q * 8192 + ti * 4096];
    }

    // prefetch x for l=0
    float2 xc[2][4];
#pragma unroll
    for (int mt = 0; mt < 2; ++mt)
#pragma unroll
        for (int r = 0; r < 4; ++r) {
            int n = n0 + 16 * mt + 4 * lq + r;
            xc[mt][r] = *(const float2*)&x[(n * L_STEPS + 0) * 2];
        }

    __syncthreads();  // one-time full sync (h init visible); drains prologue too

    int buf = 0;
#pragma unroll 1
    for (int l = 0; l < L_STEPS; ++l) {
        // Defeat LICM: fresh weight base each step so the (l-invariant)
        // B-frag loads cannot be hoisted out of the l-loop (-> 256-VGPR
        // live set -> scratch spill, the r0 bug).
        asm volatile("" : "+v"(wb_u));
        const f16* wb = (const f16*)(uintptr_t)wb_u;

        // ---- accumulator init = x-projection (fp32 exact) ----
        f32x4 acc[2][2][4];  // [ti][mt][q]
#pragma unroll
        for (int mt = 0; mt < 2; ++mt)
#pragma unroll
            for (int r = 0; r < 4; ++r) {
#pragma unroll
                for (int ti = 0; ti < 2; ++ti)
#pragma unroll
                    for (int q = 0; q < 4; ++q)
                        acc[ti][mt][q][r] = bsv[ti][q] + xc[mt][r].x * wih0[ti][q]
                                                       + xc[mt][r].y * wih1[ti][q];
            }

        // software-prefetch x for l+1 (hidden under MFMA phase; L1 is
        // thrashed by the 512 KB/step weight stream, so this matters)
        float2 xn[2][4];
        if (l + 1 < L_STEPS) {
#pragma unroll
            for (int mt = 0; mt < 2; ++mt)
#pragma unroll
                for (int r = 0; r < 4; ++r) {
                    int n = n0 + 16 * mt + 4 * lq + r;
                    xn[mt][r] = *(const float2*)&x[(n * L_STEPS + l + 1) * 2];
                }
        }

        // ---- gates += h @ W_hh^T (B streamed from L2, A from LDS) ----
        // phase p consumes slot p&1 (kb = (p+kb0)&7), loads slot (p+1)&1
        // with kb = (p+1+kb0)&7; p=7 prefetches next step's phase 0.
#pragma unroll
        for (int p = 0; p < 8; ++p) {
            int kb_c = (p + kb0) & 7;       // consumed this phase (uniform)
            int kb_n = (p + 1 + kb0) & 7;   // loaded this phase  (uniform)
#pragma unroll
            for (int ti = 0; ti < 2; ++ti)
#pragma unroll
                for (int q = 0; q < 4; ++q)
                    wbuf[(p + 1) & 1][ti][q] =
                        *(const f16x8*)&wb[kb_n * 32768 + q * 8192 + ti * 4096];

            f16x8 a0 = *(const f16x8*)&hp[buf][((kb_c * 2 + 0) * 64 + lane) * 8];
            f16x8 a1 = *(const f16x8*)&hp[buf][((kb_c * 2 + 1) * 64 + lane) * 8];
#pragma unroll
            for (int ti = 0; ti < 2; ++ti)
#pragma unroll
                for (int q = 0; q < 4; ++q) {
                    acc[ti][0][q] = __builtin_amdgcn_mfma_f32_16x16x32_f16(
                        a0, wbuf[p & 1][ti][q], acc[ti][0][q], 0, 0, 0);
                    acc[ti][1][q] = __builtin_amdgcn_mfma_f32_16x16x32_f16(
                        a1, wbuf[p & 1][ti][q], acc[ti][1][q], 0, 0, 0);
                }
        }

        // ---- elementwise LSTM update (all 4 gates in-register per lane) ----
#pragma unroll
        for (int ti = 0; ti < 2; ++ti) {
            int j   = 16 * (wave + 8 * ti) + l15;
            int kbj = j >> 5, qk = (j >> 3) & 3, e = j & 7;
#pragma unroll
            for (int mt = 0; mt < 2; ++mt)
#pragma unroll
                for (int r = 0; r < 4; ++r) {
                    float gi = acc[ti][mt][0][r];
                    float gf = acc[ti][mt][1][r];
                    float gg = acc[ti][mt][2][r];
                    float go = acc[ti][mt][3][r];
                    float cn = sigmoid_(gf) * c[ti][mt][r] + sigmoid_(gi) * tanh_(gg);
                    c[ti][mt][r] = cn;
                    float hv = sigmoid_(go) * tanh_(cn);
                    int laneA = (4 * lq + r) | (qk << 4);
                    hp[buf ^ 1][((kbj * 2 + mt) * 64 + laneA) * 8 + e] = (f16)hv;
                }
        }
        lds_barrier();  // barrier A: h_new visible (weight prefetch stays in flight)

        // ---- out[:, l, :] = h_new @ fc_w^T + fc_b (B register-resident) ----
        f32x4 facc0 = {fcbv, fcbv, fcbv, fcbv};
        f32x4 facc1 = facc0;
#pragma unroll
        for (int kb = 0; kb < 8; ++kb) {
            f16x8 a0 = *(const f16x8*)&hp[buf ^ 1][((kb * 2 + 0) * 64 + lane) * 8];
            f16x8 a1 = *(const f16x8*)&hp[buf ^ 1][((kb * 2 + 1) * 64 + lane) * 8];
            facc0 = __builtin_amdgcn_mfma_f32_16x16x32_f16(a0, fcw[kb], facc0, 0, 0, 0);
            facc1 = __builtin_amdgcn_mfma_f32_16x16x32_f16(a1, fcw[kb], facc1, 0, 0, 0);
        }
        const int o = 16 * wave + l15;
#pragma unroll
        for (int r = 0; r < 4; ++r) {
            obuf[(4 * lq + r) * OUT_DIM + o]        = facc0[r];
            obuf[(16 + 4 * lq + r) * OUT_DIM + o]   = facc1[r];
        }
        lds_barrier();  // barrier B: obuf visible (out stores stay in flight)

        // ---- cooperative, line-contiguous global write (fire-and-forget) ----
        {
            const int row = tid >> 4;
            const int gl  = ((n0 + row) * L_STEPS + l) * OUT_DIM;
#pragma unroll
            for (int half = 0; half < 2; ++half) {
                int col = (tid & 15) * 4 + half * 64;
                f32x4 v = *(const f32x4*)&obuf[row * OUT_DIM + col];
                *(f32x4*)&out[gl + col] = v;
            }
        }

#pragma unroll
        for (int mt = 0; mt < 2; ++mt)
#pragma unroll
            for (int r = 0; r < 4; ++r) xc[mt][r] = xn[mt][r];
        buf ^= 1;
    }
}

extern "C" void kernel_launch(void* const* d_in, const int* in_sizes, int n_in,
                              void* d_out, int out_size, void* d_ws, size_t ws_size,
                              hipStream_t stream) {
    const float* x    = (const float*)d_in[0];
    const float* W_ih = (const float*)d_in[1];
    const float* W_hh = (const float*)d_in[2];
    const float* b_ih = (const float*)d_in[3];
    const float* b_hh = (const float*)d_in[4];
    const float* fc_w = (const float*)d_in[5];
    const float* fc_b = (const float*)d_in[6];
    float* out = (float*)d_out;

    char* ws = (char*)d_ws;
    f16*   Wpack  = (f16*)(ws + WPACK_OFF);
    f16*   fcpack = (f16*)(ws + FCPACK_OFF);
    float* bsum   = (float*)(ws + BSUM_OFF);

    const int prep_elems = 262144 + 32768 + 1024;
    prep_kernel<<<(prep_elems + 255) / 256, 256, 0, stream>>>(
        W_hh, fc_w, b_ih, b_hh, Wpack, fcpack, bsum);

    lstm_kernel<<<NBLK, THREADS, 0, stream>>>(
        x, W_ih, Wpack, bsum, fcpack, fc_b, out);
}

// Round 3
// 426.536 us; speedup vs baseline: 2.2443x; 1.0928x over previous
//
#include <hip/hip_runtime.h>

typedef _Float16 f16;
typedef _Float16 f16x8 __attribute__((ext_vector_type(8)));
typedef float f32x4 __attribute__((ext_vector_type(4)));

// address_space(1) = global: forces global_load_* (vmcnt-only) instead of
// flat_load_* (vmcnt AND lgkmcnt). With flat loads, every lgkmcnt wait —
// including the per-step lds_barrier and each ds_read->MFMA wait — drains
// the L2 weight stream. That was the ~20k-cycle/step serializer.
typedef __attribute__((address_space(1))) const f16 gf16;
typedef __attribute__((address_space(1))) const f16x8 gf16x8;

#define N_TOT   8192
#define L_STEPS 32
#define H_DIM   256
#define G4      1024
#define OUT_DIM 128
#define BN      32
#define NBLK    256
#define THREADS 512

// workspace layout (bytes):
//   Wpack : 262144 f16 = 524288 B @ 0        (W_hh in B-frag order)
//   fcpack:  32768 f16 =  65536 B @ 524288   (fc_w in B-frag order)
//   bsum  :   1024 f32 =   4096 B @ 589824   (b_ih + b_hh)
#define WPACK_OFF  0
#define FCPACK_OFF 524288
#define BSUM_OFF   589824

__global__ __launch_bounds__(256) void prep_kernel(
    const float* __restrict__ W_hh, const float* __restrict__ fc_w,
    const float* __restrict__ b_ih, const float* __restrict__ b_hh,
    f16* __restrict__ Wpack, f16* __restrict__ fcpack, float* __restrict__ bsum)
{
    int p = blockIdx.x * blockDim.x + threadIdx.x;
    if (p < 262144) {
        // Wpack[((kb*64 + T)*64 + lane)*8 + e] = W_hh[g][k]
        // g = 16*T + (lane&15), k = 32*kb + 8*(lane>>4) + e
        int e = p & 7, lane = (p >> 3) & 63, T = (p >> 9) & 63, kb = p >> 15;
        int g = 16 * T + (lane & 15);
        int k = 32 * kb + 8 * (lane >> 4) + e;
        Wpack[p] = (f16)W_hh[g * 256 + k];
    } else if (p < 262144 + 32768) {
        int p2 = p - 262144;
        // fcpack[((kb*8 + ot)*64 + lane)*8 + e] = fc_w[o][k]
        int e = p2 & 7, lane = (p2 >> 3) & 63, ot = (p2 >> 9) & 7, kb = p2 >> 12;
        int o = 16 * ot + (lane & 15);
        int k = 32 * kb + 8 * (lane >> 4) + e;
        fcpack[p2] = (f16)fc_w[o * 256 + k];
    } else if (p < 262144 + 32768 + 1024) {
        int g = p - 262144 - 32768;
        bsum[g] = b_ih[g] + b_hh[g];
    }
}

__device__ __forceinline__ float sigmoid_(float x) {
    return 1.0f / (1.0f + __expf(-x));
}
__device__ __forceinline__ float tanh_(float x) {
    float t = __expf(-2.0f * x);
    return (1.0f - t) / (1.0f + t);
}

// LDS-only barrier: ds ops complete (lgkmcnt), but global weight loads and
// output stores stay IN FLIGHT across it (they are vmcnt-only now that the
// weight stream uses address_space(1) global loads).
__device__ __forceinline__ void lds_barrier() {
    asm volatile("s_waitcnt lgkmcnt(0)" ::: "memory");
    __builtin_amdgcn_s_barrier();
    asm volatile("" ::: "memory");
}

// 256 blocks x 512 threads (8 waves, 2 waves/SIMD, 1 block/CU).
// W_hh B-frags stream from L2 (512 KB Wpack resident per XCD L2) through a
// DEPTH-2, 3-slot register pipe: phase p consumes slot p%3; phases 0..5
// issue loads for phase p+2; phases 6,7 issue next step's phases 0,1 after
// their MFMAs (those loads fly across the elementwise/fc/store region and
// the lgkm-only barriers). A slot is thus always issued ~2 MFMA phases
// before use -> L2 latency (~300 cyc) fully hidden.
// kb sweep ROTATED per block (kb0 = (blockIdx>>3)&7) to de-hotspot the
// per-XCD L2 (32 CUs share one L2; rotation spreads the 64 KB regions).
__global__ __launch_bounds__(THREADS, 2) void lstm_kernel(
    const float* __restrict__ x, const float* __restrict__ W_ih,
    const f16* __restrict__ Wpack, const float* __restrict__ bsum,
    const f16* __restrict__ fcpack, const float* __restrict__ fc_b,
    float* __restrict__ out)
{
    __shared__ __align__(16) f16 hp[2][8192];          // h in A-frag order, dbuf
    __shared__ __align__(16) float obuf[BN * OUT_DIM]; // fc out staging, 16 KB

    const int tid  = threadIdx.x;
    const int wave = tid >> 6;
    const int lane = tid & 63;
    const int l15  = lane & 15;
    const int lq   = lane >> 4;
    const int n0   = blockIdx.x * BN;
    const int kb0  = (blockIdx.x >> 3) & 7;   // L2 de-hotspot rotation

    // ---- resident fc B-frags (8 KB/wave -> 32 VGPR) ----
    f16x8 fcw[8];
#pragma unroll
    for (int kb = 0; kb < 8; ++kb)
        fcw[kb] = *(const f16x8*)&fcpack[((kb * 8 + wave) * 64 + lane) * 8];

    // h(t=0) = 0
    for (int i = tid; i < 8192; i += THREADS) hp[0][i] = (f16)0.0f;

    // per-lane x-projection constants: g = 256*q + 16*(wave + 8*ti) + l15
    float wih0[2][4], wih1[2][4], bsv[2][4];
#pragma unroll
    for (int ti = 0; ti < 2; ++ti)
#pragma unroll
        for (int q = 0; q < 4; ++q) {
            int g = 256 * q + 16 * (wave + 8 * ti) + l15;
            wih0[ti][q] = W_ih[g * 2 + 0];
            wih1[ti][q] = W_ih[g * 2 + 1];
            bsv[ti][q]  = bsum[g];
        }
    const float fcbv = fc_b[16 * wave + l15];

    float c[2][2][4];
#pragma unroll
    for (int ti = 0; ti < 2; ++ti)
#pragma unroll
        for (int mt = 0; mt < 2; ++mt)
#pragma unroll
            for (int r = 0; r < 4; ++r) c[ti][mt][r] = 0.0f;

    // weight stream base: f16 index = kb*32768 + q*8192 + ti*4096 + wave*512 + lane*8
    unsigned long long wb_u =
        (unsigned long long)(uintptr_t)(Wpack + wave * 512 + lane * 8);

    // prologue: phase 0 (kb0) -> slot 0, phase 1 (kb0+1) -> slot 1
    f16x8 wbuf[3][2][4];  // [slot][ti][q] — slot index always compile-time
    {
        gf16* wb = (gf16*)(uintptr_t)wb_u;
        int kbA = kb0, kbB = (kb0 + 1) & 7;
#pragma unroll
        for (int ti = 0; ti < 2; ++ti)
#pragma unroll
            for (int q = 0; q < 4; ++q) {
                wbuf[0][ti][q] = *(const gf16x8*)&wb[kbA * 32768 + q * 8192 + ti * 4096];
                wbuf[1][ti][q] = *(const gf16x8*)&wb[kbB * 32768 + q * 8192 + ti * 4096];
            }
    }

    // prefetch x for l=0
    float2 xc[2][4];
#pragma unroll
    for (int mt = 0; mt < 2; ++mt)
#pragma unroll
        for (int r = 0; r < 4; ++r) {
            int n = n0 + 16 * mt + 4 * lq + r;
            xc[mt][r] = *(const float2*)&x[(n * L_STEPS + 0) * 2];
        }

    __syncthreads();  // one-time full sync (h init visible); drains prologue too

    int buf = 0;
#pragma unroll 1
    for (int l = 0; l < L_STEPS; ++l) {
        // Defeat LICM: fresh weight base each step so the (l-invariant)
        // B-frag loads cannot be hoisted out of the l-loop (-> 256-VGPR
        // live set -> scratch spill, the r0 bug).
        asm volatile("" : "+v"(wb_u));
        gf16* wb = (gf16*)(uintptr_t)wb_u;

        // ---- accumulator init = x-projection (fp32 exact) ----
        f32x4 acc[2][2][4];  // [ti][mt][q]
#pragma unroll
        for (int mt = 0; mt < 2; ++mt)
#pragma unroll
            for (int r = 0; r < 4; ++r) {
#pragma unroll
                for (int ti = 0; ti < 2; ++ti)
#pragma unroll
                    for (int q = 0; q < 4; ++q)
                        acc[ti][mt][q][r] = bsv[ti][q] + xc[mt][r].x * wih0[ti][q]
                                                       + xc[mt][r].y * wih1[ti][q];
            }

        // software-prefetch x for l+1 (L1 is thrashed by the weight stream)
        float2 xn[2][4];
        if (l + 1 < L_STEPS) {
#pragma unroll
            for (int mt = 0; mt < 2; ++mt)
#pragma unroll
                for (int r = 0; r < 4; ++r) {
                    int n = n0 + 16 * mt + 4 * lq + r;
                    xn[mt][r] = *(const float2*)&x[(n * L_STEPS + l + 1) * 2];
                }
        }

        // ---- gates += h @ W_hh^T (B streamed from L2, A from LDS) ----
#pragma unroll
        for (int p = 0; p < 8; ++p) {
            const int sc = p % 3;              // slot consumed (compile-time)
            const int sl = (p + 2) % 3;        // slot loaded   (compile-time)
            const int kb_c = (p + kb0) & 7;    // kb consumed this phase

            if (p < 6) {
                const int kb_n = (p + 2 + kb0) & 7;
#pragma unroll
                for (int ti = 0; ti < 2; ++ti)
#pragma unroll
                    for (int q = 0; q < 4; ++q)
                        wbuf[sl][ti][q] =
                            *(const gf16x8*)&wb[kb_n * 32768 + q * 8192 + ti * 4096];
            }

            f16x8 a0 = *(const f16x8*)&hp[buf][((kb_c * 2 + 0) * 64 + lane) * 8];
            f16x8 a1 = *(const f16x8*)&hp[buf][((kb_c * 2 + 1) * 64 + lane) * 8];
#pragma unroll
            for (int ti = 0; ti < 2; ++ti)
#pragma unroll
                for (int q = 0; q < 4; ++q) {
                    acc[ti][0][q] = __builtin_amdgcn_mfma_f32_16x16x32_f16(
                        a0, wbuf[sc][ti][q], acc[ti][0][q], 0, 0, 0);
                    acc[ti][1][q] = __builtin_amdgcn_mfma_f32_16x16x32_f16(
                        a1, wbuf[sc][ti][q], acc[ti][1][q], 0, 0, 0);
                }

            // cross-step prefetch: next step's phases 0,1 into slots 0,1
            // (issued AFTER this phase's MFMAs consumed those slots)
            if (p == 6) {
                const int kb_n = kb0;
#pragma unroll
                for (int ti = 0; ti < 2; ++ti)
#pragma unroll
                    for (int q = 0; q < 4; ++q)
                        wbuf[0][ti][q] =
                            *(const gf16x8*)&wb[kb_n * 32768 + q * 8192 + ti * 4096];
            }
            if (p == 7) {
                const int kb_n = (kb0 + 1) & 7;
#pragma unroll
                for (int ti = 0; ti < 2; ++ti)
#pragma unroll
                    for (int q = 0; q < 4; ++q)
                        wbuf[1][ti][q] =
                            *(const gf16x8*)&wb[kb_n * 32768 + q * 8192 + ti * 4096];
            }
        }

        // ---- elementwise LSTM update (all 4 gates in-register per lane) ----
#pragma unroll
        for (int ti = 0; ti < 2; ++ti) {
            int j   = 16 * (wave + 8 * ti) + l15;
            int kbj = j >> 5, qk = (j >> 3) & 3, e = j & 7;
#pragma unroll
            for (int mt = 0; mt < 2; ++mt)
#pragma unroll
                for (int r = 0; r < 4; ++r) {
                    float gi = acc[ti][mt][0][r];
                    float gf = acc[ti][mt][1][r];
                    float gg = acc[ti][mt][2][r];
                    float go = acc[ti][mt][3][r];
                    float cn = sigmoid_(gf) * c[ti][mt][r] + sigmoid_(gi) * tanh_(gg);
                    c[ti][mt][r] = cn;
                    float hv = sigmoid_(go) * tanh_(cn);
                    int laneA = (4 * lq + r) | (qk << 4);
                    hp[buf ^ 1][((kbj * 2 + mt) * 64 + laneA) * 8 + e] = (f16)hv;
                }
        }
        lds_barrier();  // barrier A: h_new visible (weight prefetch stays in flight)

        // ---- out[:, l, :] = h_new @ fc_w^T + fc_b (B register-resident) ----
        f32x4 facc0 = {fcbv, fcbv, fcbv, fcbv};
        f32x4 facc1 = facc0;
#pragma unroll
        for (int kb = 0; kb < 8; ++kb) {
            f16x8 a0 = *(const f16x8*)&hp[buf ^ 1][((kb * 2 + 0) * 64 + lane) * 8];
            f16x8 a1 = *(const f16x8*)&hp[buf ^ 1][((kb * 2 + 1) * 64 + lane) * 8];
            facc0 = __builtin_amdgcn_mfma_f32_16x16x32_f16(a0, fcw[kb], facc0, 0, 0, 0);
            facc1 = __builtin_amdgcn_mfma_f32_16x16x32_f16(a1, fcw[kb], facc1, 0, 0, 0);
        }
        const int o = 16 * wave + l15;
#pragma unroll
        for (int r = 0; r < 4; ++r) {
            obuf[(4 * lq + r) * OUT_DIM + o]        = facc0[r];
            obuf[(16 + 4 * lq + r) * OUT_DIM + o]   = facc1[r];
        }
        lds_barrier();  // barrier B: obuf visible (out stores stay in flight)

        // ---- cooperative, line-contiguous global write (fire-and-forget) ----
        {
            const int row = tid >> 4;
            const int gl  = ((n0 + row) * L_STEPS + l) * OUT_DIM;
#pragma unroll
            for (int half = 0; half < 2; ++half) {
                int col = (tid & 15) * 4 + half * 64;
                f32x4 v = *(const f32x4*)&obuf[row * OUT_DIM + col];
                *(f32x4*)&out[gl + col] = v;
            }
        }

#pragma unroll
        for (int mt = 0; mt < 2; ++mt)
#pragma unroll
            for (int r = 0; r < 4; ++r) xc[mt][r] = xn[mt][r];
        buf ^= 1;
    }
}

extern "C" void kernel_launch(void* const* d_in, const int* in_sizes, int n_in,
                              void* d_out, int out_size, void* d_ws, size_t ws_size,
                              hipStream_t stream) {
    const float* x    = (const float*)d_in[0];
    const float* W_ih = (const float*)d_in[1];
    const float* W_hh = (const float*)d_in[2];
    const float* b_ih = (const float*)d_in[3];
    const float* b_hh = (const float*)d_in[4];
    const float* fc_w = (const float*)d_in[5];
    const float* fc_b = (const float*)d_in[6];
    float* out = (float*)d_out;

    char* ws = (char*)d_ws;
    f16*   Wpack  = (f16*)(ws + WPACK_OFF);
    f16*   fcpack = (f16*)(ws + FCPACK_OFF);
    float* bsum   = (float*)(ws + BSUM_OFF);

    const int prep_elems = 262144 + 32768 + 1024;
    prep_kernel<<<(prep_elems + 255) / 256, 256, 0, stream>>>(
        W_hh, fc_w, b_ih, b_hh, Wpack, fcpack, bsum);

    lstm_kernel<<<NBLK, THREADS, 0, stream>>>(
        x, W_ih, Wpack, bsum, fcpack, fc_b, out);
}